// Round 6
// baseline (7441.171 us; speedup 1.0000x reference)
//
#include <hip/hip_runtime.h>
#include <hip/hip_bf16.h>
#include <math.h>

typedef float f32x4 __attribute__((ext_vector_type(4)));

#define T_    2048
#define DM_   2048
#define KV_   1024
#define L2T_  0.4152410118609203f     // log2(10000)/32

// ---------------------------------------------------------------------------
// Naive f32 QKV GEMM: C = A(4096x2048) @ B(2048x3072). cols<2048 -> qy (f32,
// stride 2048), cols>=2048 -> kv (f32, stride 1024). 64x64 tile, 4x4/thread.
// ---------------------------------------------------------------------------
__global__ __launch_bounds__(256) void qkv_gemm_naive(
    const float* __restrict__ A, const float* __restrict__ B,
    float* __restrict__ Cq, float* __restrict__ Ckv, int M, int N, int K){
  __shared__ float As[64 * 20];
  __shared__ float Bs[16 * 68];
  const int tid = threadIdx.x, tx = tid & 15, ty = tid >> 4;
  const int m0 = blockIdx.y * 64, n0 = blockIdx.x * 64;
  const int ar = tid >> 2, ac = (tid & 3) * 4;
  const int br = tid >> 4, bc = (tid & 15) * 4;

  float acc[4][4];
#pragma unroll
  for (int i = 0; i < 4; ++i)
#pragma unroll
    for (int j = 0; j < 4; ++j) acc[i][j] = 0.f;

  for (int kb = 0; kb < K; kb += 16){
    __syncthreads();
    *(f32x4*)&As[ar * 20 + ac] = *(const f32x4*)&A[(size_t)(m0 + ar) * K + kb + ac];
    *(f32x4*)&Bs[br * 68 + bc] = *(const f32x4*)&B[(size_t)(kb + br) * N + n0 + bc];
    __syncthreads();
#pragma unroll
    for (int kk = 0; kk < 16; ++kk){
      const f32x4 bv = *(const f32x4*)&Bs[kk * 68 + tx * 4];
#pragma unroll
      for (int i = 0; i < 4; ++i){
        const float av = As[(ty * 4 + i) * 20 + kk];
#pragma unroll
        for (int j = 0; j < 4; ++j) acc[i][j] += av * bv[j];
      }
    }
  }

#pragma unroll
  for (int i = 0; i < 4; ++i)
#pragma unroll
    for (int j = 0; j < 4; ++j){
      const int m = m0 + ty * 4 + i, n = n0 + tx * 4 + j;
      if (n < DM_) Cq[(size_t)m * DM_ + n] = acc[i][j];
      else         Ckv[(size_t)m * KV_ + (n - DM_)] = acc[i][j];
    }
}

// ---------------------------------------------------------------------------
// Naive f32 proj GEMM: out(f32) = Y(4096x2048 f32) @ W(2048x2048 f32).
// ---------------------------------------------------------------------------
__global__ __launch_bounds__(256) void proj_gemm_naive(
    const float* __restrict__ A, const float* __restrict__ B,
    float* __restrict__ C, int M, int N, int K){
  __shared__ float As[64 * 20];
  __shared__ float Bs[16 * 68];
  const int tid = threadIdx.x, tx = tid & 15, ty = tid >> 4;
  const int m0 = blockIdx.y * 64, n0 = blockIdx.x * 64;
  const int ar = tid >> 2, ac = (tid & 3) * 4;
  const int br = tid >> 4, bc = (tid & 15) * 4;

  float acc[4][4];
#pragma unroll
  for (int i = 0; i < 4; ++i)
#pragma unroll
    for (int j = 0; j < 4; ++j) acc[i][j] = 0.f;

  for (int kb = 0; kb < K; kb += 16){
    __syncthreads();
    *(f32x4*)&As[ar * 20 + ac] = *(const f32x4*)&A[(size_t)(m0 + ar) * K + kb + ac];
    *(f32x4*)&Bs[br * 68 + bc] = *(const f32x4*)&B[(size_t)(kb + br) * N + n0 + bc];
    __syncthreads();
#pragma unroll
    for (int kk = 0; kk < 16; ++kk){
      const f32x4 bv = *(const f32x4*)&Bs[kk * 68 + tx * 4];
#pragma unroll
      for (int i = 0; i < 4; ++i){
        const float av = As[(ty * 4 + i) * 20 + kk];
#pragma unroll
        for (int j = 0; j < 4; ++j) acc[i][j] += av * bv[j];
      }
    }
  }

#pragma unroll
  for (int i = 0; i < 4; ++i)
#pragma unroll
    for (int j = 0; j < 4; ++j){
      const int m = m0 + ty * 4 + i, n = n0 + tx * 4 + j;
      C[(size_t)m * N + n] = acc[i][j];
    }
}

// ---------------------------------------------------------------------------
// f32 RoPE in place: q (32 heads, fold 1/8 scale) and k (8 groups).
// One block per row (b*T+t); 1280 pairs, 5 per thread.
// ---------------------------------------------------------------------------
__global__ __launch_bounds__(256) void rope_qk_f32(
    float* __restrict__ qm, float* __restrict__ kvm){
  const int row = blockIdx.x;
  const int t = row & (T_ - 1);
#pragma unroll
  for (int it = 0; it < 5; ++it){
    const int p = threadIdx.x + it * 256;
    const int i = p & 31;
    float sv, cv;
    sincosf((float)t * exp2f(-(float)i * L2T_), &sv, &cv);
    float* ptr; float scale;
    if (p < 1024){ ptr = qm + (size_t)row * DM_ + (p >> 5) * 64 + 2 * i; scale = 0.125f; }
    else { ptr = kvm + (size_t)row * KV_ + ((p - 1024) >> 5) * 64 + 2 * i; scale = 1.f; }
    const float a = ptr[0], b = ptr[1];
    ptr[0] = (a * cv - b * sv) * scale;
    ptr[1] = (a * sv + b * cv) * scale;
  }
}

// ---------------------------------------------------------------------------
// Naive attention: one block per (b, h, t). Scores in LDS, two-pass softmax,
// y written in place over q (this block is the only reader of that q slice).
// ---------------------------------------------------------------------------
__global__ __launch_bounds__(256) void attn_naive(
    float* __restrict__ qy, const float* __restrict__ kv){
  __shared__ float qs[64];
  __shared__ float sc[2048];
  __shared__ float red[256];
  __shared__ float of[256];
  const int tid = threadIdx.x;
  const int t = blockIdx.x, h = blockIdx.y, b = blockIdx.z;
  const int g = h >> 2;
  const float* kbase = kv + (size_t)b * T_ * KV_ + g * 64;
  const float* vbase = kv + (size_t)b * T_ * KV_ + 512 + g * 64;
  float* qrow = qy + ((size_t)b * T_ + t) * DM_ + h * 64;

  if (tid < 64) qs[tid] = qrow[tid];
  __syncthreads();

  // phase 1: scores (q pre-scaled by 1/8)
  float lm = -INFINITY;
  for (int key = tid; key <= t; key += 256){
    const float* kr = kbase + (size_t)key * KV_;
    float dot = 0.f;
#pragma unroll
    for (int d = 0; d < 64; d += 4){
      const f32x4 kq = *(const f32x4*)(kr + d);
      const f32x4 qq = *(const f32x4*)(qs + d);
      dot += kq[0]*qq[0] + kq[1]*qq[1] + kq[2]*qq[2] + kq[3]*qq[3];
    }
    sc[key] = dot;
    lm = fmaxf(lm, dot);
  }
  red[tid] = lm;
  __syncthreads();
  for (int s = 128; s > 0; s >>= 1){
    if (tid < s) red[tid] = fmaxf(red[tid], red[tid + s]);
    __syncthreads();
  }
  const float mrow = red[0];
  __syncthreads();

  // phase 2: exp + sum
  float ls = 0.f;
  for (int key = tid; key <= t; key += 256){
    const float p = expf(sc[key] - mrow);
    sc[key] = p;
    ls += p;
  }
  red[tid] = ls;
  __syncthreads();
  for (int s = 128; s > 0; s >>= 1){
    if (tid < s) red[tid] += red[tid + s];
    __syncthreads();
  }
  const float lrow = red[0];

  // phase 3: O[d] = sum_key p * V[key][d]
  const int d = tid & 63, seg = tid >> 6;
  float o = 0.f;
  for (int key = seg; key <= t; key += 4)
    o += sc[key] * vbase[(size_t)key * KV_ + d];
  of[tid] = o;
  __syncthreads();
  if (tid < 64)
    qrow[tid] = (of[tid] + of[tid + 64] + of[tid + 128] + of[tid + 192]) / lrow;
}

// ---------------------------------------------------------------------------
extern "C" void kernel_launch(void* const* d_in, const int* in_sizes, int n_in,
                              void* d_out, int out_size, void* d_ws, size_t ws_size,
                              hipStream_t stream) {
  // Select inputs by element count (robust to ordering).
  const float *x = nullptr, *w_qkv = nullptr, *w_proj = nullptr;
  for (int i = 0; i < n_in; ++i){
    if (in_sizes[i] == 8388608)      x      = (const float*)d_in[i];
    else if (in_sizes[i] == 6291456) w_qkv  = (const float*)d_in[i];
    else if (in_sizes[i] == 4194304) w_proj = (const float*)d_in[i];
  }
  float* out = (float*)d_out;   // reference output dtype is float32

  // ws (50.3 MB): qy f32 @0 (33.5MB) ; kv f32 @33.5MB (16.8MB)
  char* ws = (char*)d_ws;
  float* qy  = (float*)ws;
  float* kvb = (float*)(ws + (size_t)33554432);

  qkv_gemm_naive<<<dim3(48, 64), 256, 0, stream>>>(x, w_qkv, qy, kvb, 4096, 3072, 2048);
  rope_qk_f32<<<4096, 256, 0, stream>>>(qy, kvb);
  attn_naive<<<dim3(2048, 32, 2), 256, 0, stream>>>(qy, kvb);
  proj_gemm_naive<<<dim3(32, 64), 256, 0, stream>>>(qy, w_proj, out, 4096, 2048, 2048);
}